// Round 1
// baseline (108.222 us; speedup 1.0000x reference)
//
#include <hip/hip_runtime.h>

#define S   500
#define B   32
#define T   40
#define L   20
#define NT  10000
#define NEG (-1e9f)

// Kernel 1: em[t,b,s] = sum_l logE[s, stories[b,t,l]]  -> written into d_out[t,b,s]
// One block per state s; row logE[s,:] staged in LDS (40 KB).
__global__ __launch_bounds__(256) void emission_kernel(
    const float* __restrict__ logE, const int* __restrict__ stories,
    float* __restrict__ out)
{
    __shared__ float row[NT];
    const int s   = blockIdx.x;
    const int tid = threadIdx.x;

    // coalesced float4 stage of one 10000-float row
    const float4* src = (const float4*)(logE + (size_t)s * NT);
    float4* dst = (float4*)row;
    for (int i = tid; i < NT / 4; i += 256) dst[i] = src[i];
    __syncthreads();

    for (int p = tid; p < B * T; p += 256) {            // p = b*T + t
        const int* tk = stories + p * L;
        float acc = 0.f;
        #pragma unroll
        for (int l = 0; l < L; ++l) acc += row[tk[l]];
        const int b = p / T, t = p % T;
        out[((size_t)t * B + b) * S + s] = acc;
    }
}

// Kernel 2: forward recursion, one block per batch element b.
// alpha kept in LDS double buffer; 7 sparse transition entries per state in registers.
__global__ __launch_bounds__(512) void forward_kernel(
    const float* __restrict__ priors, const float* __restrict__ logT,
    float* __restrict__ out)
{
    __shared__ float alpha[2][512];
    const int s = threadIdx.x;
    const int b = blockIdx.x;
    const bool act = (s < S);

    float tv[7];
    int   dd[7];
    if (act) {
        const int x = s % 10, y = (s / 10) % 10, z = s / 100;
        const float* rowT = logT + (size_t)s * S;
        dd[0] = s;                          tv[0] = rowT[s];
        dd[1] = (x + 1 < 10) ? s + 1   : s; tv[1] = (x + 1 < 10) ? rowT[s + 1]   : NEG;
        dd[2] = (x - 1 >= 0) ? s - 1   : s; tv[2] = (x - 1 >= 0) ? rowT[s - 1]   : NEG;
        dd[3] = (y + 1 < 10) ? s + 10  : s; tv[3] = (y + 1 < 10) ? rowT[s + 10]  : NEG;
        dd[4] = (y - 1 >= 0) ? s - 10  : s; tv[4] = (y - 1 >= 0) ? rowT[s - 10]  : NEG;
        dd[5] = (z + 1 < 5)  ? s + 100 : s; tv[5] = (z + 1 < 5)  ? rowT[s + 100] : NEG;
        dd[6] = (z + 2 < 5)  ? s + 200 : s; tv[6] = (z + 2 < 5)  ? rowT[s + 200] : NEG;
    }

    const size_t base = (size_t)b * S + s;
    float a0 = 0.f;
    if (act) {
        a0 = out[base] + priors[s];   // em[0,b,s] + log_priors[s]
        out[base] = a0;
    }
    alpha[0][s] = a0;

    float em_next = 0.f;
    if (act) em_next = out[(size_t)B * S + base];   // prefetch em[1]
    __syncthreads();

    for (int t = 1; t < T; ++t) {
        const int cur = t & 1, prev = cur ^ 1;
        const float em_t = em_next;
        if (act && t + 1 < T) em_next = out[(size_t)(t + 1) * B * S + base];

        float a = 0.f;
        if (act) {
            const float v0 = tv[0] + alpha[prev][dd[0]];
            const float v1 = tv[1] + alpha[prev][dd[1]];
            const float v2 = tv[2] + alpha[prev][dd[2]];
            const float v3 = tv[3] + alpha[prev][dd[3]];
            const float v4 = tv[4] + alpha[prev][dd[4]];
            const float v5 = tv[5] + alpha[prev][dd[5]];
            const float v6 = tv[6] + alpha[prev][dd[6]];
            float m = fmaxf(fmaxf(fmaxf(v0, v1), fmaxf(v2, v3)),
                            fmaxf(fmaxf(v4, v5), v6));
            float sum = __expf(v0 - m) + __expf(v1 - m) + __expf(v2 - m) +
                        __expf(v3 - m) + __expf(v4 - m) + __expf(v5 - m) +
                        __expf(v6 - m);
            a = em_t + m + __logf(sum);
            out[(size_t)t * B * S + base] = a;
        }
        alpha[cur][s] = a;
        __syncthreads();
    }
}

extern "C" void kernel_launch(void* const* d_in, const int* in_sizes, int n_in,
                              void* d_out, int out_size, void* d_ws, size_t ws_size,
                              hipStream_t stream) {
    const float* priors  = (const float*)d_in[0];
    const float* logT    = (const float*)d_in[1];
    const float* logE    = (const float*)d_in[2];
    const int*   stories = (const int*)d_in[3];
    float* out = (float*)d_out;

    emission_kernel<<<S, 256, 0, stream>>>(logE, stories, out);
    forward_kernel<<<B, 512, 0, stream>>>(priors, logT, out);
}

// Round 2
// 99.773 us; speedup vs baseline: 1.0847x; 1.0847x over previous
//
#include <hip/hip_runtime.h>

#define S   500
#define B   32
#define T   40
#define L   20
#define NT  10000
#define NEG (-1e9f)

// Kernel 1: em[t,b,s] = sum_l logE[s, stories[b,t,l]] (+ priors[s] at t=0)
// -> written into d_out[t,b,s]. Two states per block; both rows staged in LDS
// (80 KB). Token int4 loads feed both accumulators; paired float2 stores.
__global__ __launch_bounds__(512) void emission_kernel(
    const float* __restrict__ logE, const int* __restrict__ stories,
    const float* __restrict__ priors, float* __restrict__ out)
{
    __shared__ float row0[NT];
    __shared__ float row1[NT];
    const int s0  = blockIdx.x * 2;      // 250 blocks -> states {s0, s0+1}
    const int tid = threadIdx.x;

    // coalesced float4 stage of two 10000-float rows
    const float4* a  = (const float4*)(logE + (size_t)s0 * NT);
    const float4* bsrc = (const float4*)(logE + (size_t)(s0 + 1) * NT);
    float4* d0 = (float4*)row0;
    float4* d1 = (float4*)row1;
    for (int i = tid; i < NT / 4; i += 512) { d0[i] = a[i]; d1[i] = bsrc[i]; }
    __syncthreads();

    const float p0 = priors[s0], p1 = priors[s0 + 1];
    for (int p = tid; p < B * T; p += 512) {            // p = b*T + t
        const int4* tk = (const int4*)(stories + p * L);  // 80B-aligned
        float acc0 = 0.f, acc1 = 0.f;
        #pragma unroll
        for (int q = 0; q < L / 4; ++q) {
            const int4 v = tk[q];
            acc0 += row0[v.x] + row0[v.y] + row0[v.z] + row0[v.w];
            acc1 += row1[v.x] + row1[v.y] + row1[v.z] + row1[v.w];
        }
        const int b = p / T, t = p % T;
        if (t == 0) { acc0 += p0; acc1 += p1; }
        *(float2*)(out + ((size_t)t * B + b) * S + s0) = make_float2(acc0, acc1);
    }
}

// Kernel 2: forward recursion, one block per batch element b.
// alpha in LDS double buffer; own-state alpha kept in a register (6 LDS
// reads/step instead of 7); em[t+1] prefetched one step ahead.
__global__ __launch_bounds__(512) void forward_kernel(
    const float* __restrict__ logT, float* __restrict__ out)
{
    __shared__ float alpha[2][512];
    const int s = threadIdx.x;
    const int b = blockIdx.x;
    const bool act = (s < S);

    float tv[7];
    int   dd[7];   // dd[0] unused (self in register)
    if (act) {
        const int x = s % 10, y = (s / 10) % 10, z = s / 100;
        const float* rowT = logT + (size_t)s * S;
        tv[0] = rowT[s];
        dd[1] = (x + 1 < 10) ? s + 1   : s; tv[1] = (x + 1 < 10) ? rowT[s + 1]   : NEG;
        dd[2] = (x - 1 >= 0) ? s - 1   : s; tv[2] = (x - 1 >= 0) ? rowT[s - 1]   : NEG;
        dd[3] = (y + 1 < 10) ? s + 10  : s; tv[3] = (y + 1 < 10) ? rowT[s + 10]  : NEG;
        dd[4] = (y - 1 >= 0) ? s - 10  : s; tv[4] = (y - 1 >= 0) ? rowT[s - 10]  : NEG;
        dd[5] = (z + 1 < 5)  ? s + 100 : s; tv[5] = (z + 1 < 5)  ? rowT[s + 100] : NEG;
        dd[6] = (z + 2 < 5)  ? s + 200 : s; tv[6] = (z + 2 < 5)  ? rowT[s + 200] : NEG;
    }

    const size_t base = (size_t)b * S + s;
    float self = 0.f;                       // alpha[t-1][s] register copy
    if (act) self = out[base];              // em[0] already includes prior
    alpha[0][s] = self;

    float em_next = 0.f;
    if (act) em_next = out[(size_t)B * S + base];   // prefetch em[1]
    __syncthreads();

    for (int t = 1; t < T; ++t) {
        const int cur = t & 1, prev = cur ^ 1;
        const float em_t = em_next;
        if (act && t + 1 < T) em_next = out[(size_t)(t + 1) * B * S + base];

        float a = 0.f;
        if (act) {
            const float v0 = tv[0] + self;
            const float v1 = tv[1] + alpha[prev][dd[1]];
            const float v2 = tv[2] + alpha[prev][dd[2]];
            const float v3 = tv[3] + alpha[prev][dd[3]];
            const float v4 = tv[4] + alpha[prev][dd[4]];
            const float v5 = tv[5] + alpha[prev][dd[5]];
            const float v6 = tv[6] + alpha[prev][dd[6]];
            float m = fmaxf(fmaxf(fmaxf(v0, v1), fmaxf(v2, v3)),
                            fmaxf(fmaxf(v4, v5), v6));
            float sum = __expf(v0 - m) + __expf(v1 - m) + __expf(v2 - m) +
                        __expf(v3 - m) + __expf(v4 - m) + __expf(v5 - m) +
                        __expf(v6 - m);
            a = em_t + m + __logf(sum);
            out[(size_t)t * B * S + base] = a;
        }
        alpha[cur][s] = a;
        self = a;
        __syncthreads();
    }
}

extern "C" void kernel_launch(void* const* d_in, const int* in_sizes, int n_in,
                              void* d_out, int out_size, void* d_ws, size_t ws_size,
                              hipStream_t stream) {
    const float* priors  = (const float*)d_in[0];
    const float* logT    = (const float*)d_in[1];
    const float* logE    = (const float*)d_in[2];
    const int*   stories = (const int*)d_in[3];
    float* out = (float*)d_out;

    emission_kernel<<<S / 2, 512, 0, stream>>>(logE, stories, priors, out);
    forward_kernel<<<B, 512, 0, stream>>>(logT, out);
}

// Round 3
// 99.054 us; speedup vs baseline: 1.0925x; 1.0073x over previous
//
#include <hip/hip_runtime.h>

#define S   500
#define B   32
#define T   40
#define L   20
#define NT  10000
#define NEG (-1e9f)

// Kernel 1: em[t,b,s] = sum_l logE[s, stories[b,t,l]] (+ priors[s] at t=0)
// -> d_out[t,b,s]. Two states per block; rows stored INTERLEAVED in LDS as
// float2 so each token gather is one ds_read_b64 (halves LDS issue count).
__global__ __launch_bounds__(512) void emission_kernel(
    const float* __restrict__ logE, const int* __restrict__ stories,
    const float* __restrict__ priors, float* __restrict__ out)
{
    __shared__ float2 pair[NT];          // pair[tok] = {row_s0[tok], row_s1[tok]}
    const int s0  = blockIdx.x * 2;      // 250 blocks -> states {s0, s0+1}
    const int tid = threadIdx.x;

    const float* r0 = logE + (size_t)s0 * NT;
    const float* r1 = r0 + NT;
    // coalesced 4B loads from both rows, interleaved ds_write_b64
    for (int i = tid; i < NT; i += 512)
        pair[i] = make_float2(r0[i], r1[i]);
    __syncthreads();

    const float p0 = priors[s0], p1 = priors[s0 + 1];
    for (int p = tid; p < B * T; p += 512) {            // p = b*T + t
        const int4* tk = (const int4*)(stories + p * L);  // 80B-aligned
        float acc0 = 0.f, acc1 = 0.f;
        #pragma unroll
        for (int q = 0; q < L / 4; ++q) {
            const int4 v = tk[q];
            float2 a = pair[v.x], b2 = pair[v.y], c = pair[v.z], d = pair[v.w];
            acc0 += a.x + b2.x + c.x + d.x;
            acc1 += a.y + b2.y + c.y + d.y;
        }
        const int b = p / T, t = p % T;
        if (t == 0) { acc0 += p0; acc1 += p1; }
        *(float2*)(out + ((size_t)t * B + b) * S + s0) = make_float2(acc0, acc1);
    }
}

// Kernel 2: forward recursion, one block per batch element b.
// Padded alpha double-buffer + compile-time neighbor offsets so the compiler
// can merge the 6 neighbor reads into 3 ds_read2_b32. Invalid neighbors are
// masked by tv = NEG (pad entries are finite zeros, init'd below).
__global__ __launch_bounds__(512) void forward_kernel(
    const float* __restrict__ logT, float* __restrict__ out)
{
    constexpr int PAD = 16, AN = 768;    // front pad 16, back pad >= 200
    __shared__ float abuf[2][AN];
    const int s = threadIdx.x;
    const int b = blockIdx.x;
    const bool act = (s < S);
    const int i = s + PAD;

    // init pads (and everything) to finite zeros — LDS is undefined at entry
    for (int k = s; k < AN; k += 512) { abuf[0][k] = 0.f; abuf[1][k] = 0.f; }

    float tv0 = NEG, tv1 = NEG, tv2 = NEG, tv3 = NEG, tv4 = NEG, tv5 = NEG, tv6 = NEG;
    if (act) {
        const int x = s % 10, y = (s / 10) % 10, z = s / 100;
        const float* rowT = logT + (size_t)s * S;
        tv0 = rowT[s];
        if (x + 1 < 10) tv1 = rowT[s + 1];
        if (x - 1 >= 0) tv2 = rowT[s - 1];
        if (y + 1 < 10) tv3 = rowT[s + 10];
        if (y - 1 >= 0) tv4 = rowT[s - 10];
        if (z + 1 < 5)  tv5 = rowT[s + 100];
        if (z + 2 < 5)  tv6 = rowT[s + 200];
    }

    const size_t base = (size_t)b * S + s;
    float self = 0.f;                       // alpha[t-1][s] register copy
    if (act) self = out[base];              // em[0] already includes prior
    abuf[0][i] = self;

    float em_next = 0.f;
    if (act) em_next = out[(size_t)B * S + base];   // prefetch em[1]
    __syncthreads();

    const float* ap = abuf[0];
    float*       an = abuf[1];

    for (int t = 1; t < T; ++t) {
        const float em_t = em_next;
        if (act && t + 1 < T) em_next = out[(size_t)(t + 1) * B * S + base];

        float a = 0.f;
        if (act) {
            // compile-time offsets from one base -> 3x ds_read2_b32
            const float v0 = tv0 + self;
            const float v1 = tv1 + ap[i + 1];
            const float v2 = tv2 + ap[i - 1];
            const float v3 = tv3 + ap[i + 10];
            const float v4 = tv4 + ap[i - 10];
            const float v5 = tv5 + ap[i + 100];
            const float v6 = tv6 + ap[i + 200];
            float m = fmaxf(fmaxf(fmaxf(v0, v1), fmaxf(v2, v3)),
                            fmaxf(fmaxf(v4, v5), v6));
            float sum = __expf(v0 - m) + __expf(v1 - m) + __expf(v2 - m) +
                        __expf(v3 - m) + __expf(v4 - m) + __expf(v5 - m) +
                        __expf(v6 - m);
            a = em_t + m + __logf(sum);
            out[(size_t)t * B * S + base] = a;
        }
        an[i] = a;
        self = a;
        float* tmp = an; an = (float*)ap; ap = tmp;   // ping-pong
        __syncthreads();
    }
}

extern "C" void kernel_launch(void* const* d_in, const int* in_sizes, int n_in,
                              void* d_out, int out_size, void* d_ws, size_t ws_size,
                              hipStream_t stream) {
    const float* priors  = (const float*)d_in[0];
    const float* logT    = (const float*)d_in[1];
    const float* logE    = (const float*)d_in[2];
    const int*   stories = (const int*)d_in[3];
    float* out = (float*)d_out;

    emission_kernel<<<S / 2, 512, 0, stream>>>(logE, stories, priors, out);
    forward_kernel<<<B, 512, 0, stream>>>(logT, out);
}